// Round 5
// baseline (345.421 us; speedup 1.0000x reference)
//
#include <hip/hip_runtime.h>
#include <hip/hip_bf16.h>
#include <stdint.h>

#define HEADS 16
#define DIMH  64
#define SEQN  2048
#define SEQM  2048
#define NB    4
#define EDIM  1024
#define KD    1024

using bf16_t = __bf16;
using bf16x8 = __attribute__((ext_vector_type(8))) bf16_t;
using f32x4  = __attribute__((ext_vector_type(4))) float;

__device__ __forceinline__ unsigned short f2bf(float f) {
  union { float f; uint32_t u; } v; v.f = f;
  uint32_t u = v.u;
  u += 0x7fffu + ((u >> 16) & 1u);   // round-to-nearest-even
  return (unsigned short)(u >> 16);
}

#if __has_builtin(__builtin_amdgcn_cvt_pk_bf16_f32)
typedef __bf16 bf16x2_t __attribute__((ext_vector_type(2)));
__device__ __forceinline__ uint32_t pk_bf16(float a, float b) {
  union { bf16x2_t v; uint32_t u; } c;
  c.v = __builtin_amdgcn_cvt_pk_bf16_f32(a, b);  // low = a, high = b
  return c.u;
}
#else
__device__ __forceinline__ uint32_t pk_bf16(float a, float b) {
  union { __hip_bfloat162 v; uint32_t u; } c;
  c.v = __float22bfloat162_rn(float2{a, b});
  return c.u;
}
#endif

#if __has_builtin(__builtin_amdgcn_exp2f)
__device__ __forceinline__ float fexp2(float x) { return __builtin_amdgcn_exp2f(x); }
#else
__device__ __forceinline__ float fexp2(float x) { return exp2f(x); }
#endif

__device__ __forceinline__ void async16(const void* g, void* l) {
  __builtin_amdgcn_global_load_lds(
      (__attribute__((address_space(1))) void*)(g),
      (__attribute__((address_space(3))) void*)(l), 16, 0, 0);
}

__device__ __forceinline__ bf16x8 ldsv(const unsigned short* p) {
  return *(const bf16x8*)p;
}

// ---------------- fp32 -> bf16 converts (fused, 2 launches) ----------------
__global__ __launch_bounds__(256)
void cvt2(const float4* __restrict__ a, const float4* __restrict__ b,
          ushort4* __restrict__ oa, ushort4* __restrict__ ob, int blocks_per_seg) {
  const int seg = blockIdx.x / blocks_per_seg;
  const int i = (blockIdx.x - seg * blocks_per_seg) * 256 + threadIdx.x;
  const float4* in = seg ? b : a;
  ushort4* out = seg ? ob : oa;
  float4 v = in[i];
  ushort4 o;
  o.x = f2bf(v.x); o.y = f2bf(v.y); o.z = f2bf(v.z); o.w = f2bf(v.w);
  out[i] = o;
}

__global__ __launch_bounds__(256)
void cvt4(const float4* __restrict__ a, const float4* __restrict__ b,
          const float4* __restrict__ c, const float4* __restrict__ d,
          ushort4* __restrict__ oa, ushort4* __restrict__ ob,
          ushort4* __restrict__ oc, ushort4* __restrict__ od, int blocks_per_seg) {
  const int seg = blockIdx.x / blocks_per_seg;
  const int i = (blockIdx.x - seg * blocks_per_seg) * 256 + threadIdx.x;
  const float4* in = (seg == 0) ? a : (seg == 1) ? b : (seg == 2) ? c : d;
  ushort4* out = (seg == 0) ? oa : (seg == 1) ? ob : (seg == 2) ? oc : od;
  float4 v = in[i];
  ushort4 o;
  o.x = f2bf(v.x); o.y = f2bf(v.y); o.z = f2bf(v.z); o.w = f2bf(v.w);
  out[i] = o;
}

// ---------------- fused Q/K/V projection GEMM ----------------
// blockIdx.z: 0 -> Q = x*Wq^T (row-major bf16, pre-scaled by scale*log2e)
//             1 -> K = ctx*Wk^T (row-major bf16)
//             2 -> V^T = (ctx*Wv^T)^T as [b][h][d][m] bf16
// 1536 blocks total = 6/CU: kills inter-GEMM launch bubbles, triples TLP.
__global__ __launch_bounds__(256)
void gemm_qkv(const unsigned short* __restrict__ xb,
              const unsigned short* __restrict__ cb,
              const unsigned short* __restrict__ wqb,
              const unsigned short* __restrict__ wkb,
              const unsigned short* __restrict__ wvb,
              unsigned short* __restrict__ Qb,
              unsigned short* __restrict__ Kb,
              unsigned short* __restrict__ Vtb,
              float qscale)
{
  __shared__ __align__(16) unsigned short As[128 * 32];
  __shared__ __align__(16) unsigned short Bs[128 * 32];
  const int t   = threadIdx.x;
  const int wv  = t >> 6;
  const int ln  = t & 63;
  const int l15 = ln & 15;
  const int qd  = ln >> 4;
  const int z   = blockIdx.z;
  const int n0  = blockIdx.x * 128;
  const int m0  = blockIdx.y * 128;
  const int wm  = (wv >> 1) * 64;
  const int wn  = (wv & 1) * 64;

  const unsigned short* A = (z == 0) ? xb : cb;
  const unsigned short* W = (z == 0) ? wqb : (z == 1) ? wkb : wvb;

  const f32x4 vzero = {0.f, 0.f, 0.f, 0.f};
  f32x4 acc[4][4];
#pragma unroll
  for (int i = 0; i < 4; ++i)
#pragma unroll
    for (int j = 0; j < 4; ++j) acc[i][j] = vzero;

  for (int k0 = 0; k0 < KD; k0 += 32) {
    __syncthreads();
#pragma unroll
    for (int l = 0; l < 2; ++l) {
      const int i = l * 256 + wv * 64 + ln;   // 0..511
      const int row = i >> 2, ch = i & 3;     // 128 rows x 4 chunks(16B)
      async16(A + (size_t)(m0 + row) * KD + k0 + ch * 8, As + i * 8);
      async16(W + (size_t)(n0 + row) * KD + k0 + ch * 8, Bs + i * 8);
    }
    __syncthreads();
    bf16x8 af[4], bfr[4];
#pragma unroll
    for (int mt = 0; mt < 4; ++mt)
      af[mt] = ldsv(As + (wm + mt * 16 + l15) * 32 + qd * 8);
#pragma unroll
    for (int nt = 0; nt < 4; ++nt)
      bfr[nt] = ldsv(Bs + (wn + nt * 16 + l15) * 32 + qd * 8);
#pragma unroll
    for (int mt = 0; mt < 4; ++mt)
#pragma unroll
      for (int nt = 0; nt < 4; ++nt)
        acc[mt][nt] = __builtin_amdgcn_mfma_f32_16x16x32_bf16(af[mt], bfr[nt], acc[mt][nt], 0, 0, 0);
  }

  // epilogue: C/D layout col=l15, row=qd*4+r
  const float scale = (z == 0) ? qscale : 1.0f;
#pragma unroll
  for (int mt = 0; mt < 4; ++mt) {
#pragma unroll
    for (int nt = 0; nt < 4; ++nt) {
      const int col   = n0 + wn + nt * 16 + l15;
      const int rbase = m0 + wm + mt * 16 + qd * 4;
      if (z < 2) {
        unsigned short* outb = (z == 0) ? Qb : Kb;
#pragma unroll
        for (int r = 0; r < 4; ++r)
          outb[(size_t)(rbase + r) * EDIM + col] = f2bf(acc[mt][nt][r] * scale);
      } else {
        const int b = rbase >> 11, m = rbase & 2047;
        const int h = col >> 6,   d = col & 63;
        ushort4 o;
        o.x = f2bf(acc[mt][nt][0]); o.y = f2bf(acc[mt][nt][1]);
        o.z = f2bf(acc[mt][nt][2]); o.w = f2bf(acc[mt][nt][3]);
        *(ushort4*)(Vtb + ((size_t)(b * HEADS + h) * DIMH + d) * SEQM + m) = o;
      }
    }
  }
}

// ---------------- output projection GEMM (fp32 out + bias) ----------------
__global__ __launch_bounds__(256)
void gemm_out(const unsigned short* __restrict__ A,
              const unsigned short* __restrict__ W,
              float* __restrict__ outf,
              const float* __restrict__ bias)
{
  __shared__ __align__(16) unsigned short As[128 * 32];
  __shared__ __align__(16) unsigned short Bs[128 * 32];
  const int t   = threadIdx.x;
  const int wv  = t >> 6;
  const int ln  = t & 63;
  const int l15 = ln & 15;
  const int qd  = ln >> 4;
  const int n0  = blockIdx.x * 128;
  const int m0  = blockIdx.y * 128;
  const int wm  = (wv >> 1) * 64;
  const int wn  = (wv & 1) * 64;

  const f32x4 vzero = {0.f, 0.f, 0.f, 0.f};
  f32x4 acc[4][4];
#pragma unroll
  for (int i = 0; i < 4; ++i)
#pragma unroll
    for (int j = 0; j < 4; ++j) acc[i][j] = vzero;

  for (int k0 = 0; k0 < KD; k0 += 32) {
    __syncthreads();
#pragma unroll
    for (int l = 0; l < 2; ++l) {
      const int i = l * 256 + wv * 64 + ln;
      const int row = i >> 2, ch = i & 3;
      async16(A + (size_t)(m0 + row) * KD + k0 + ch * 8, As + i * 8);
      async16(W + (size_t)(n0 + row) * KD + k0 + ch * 8, Bs + i * 8);
    }
    __syncthreads();
    bf16x8 af[4], bfr[4];
#pragma unroll
    for (int mt = 0; mt < 4; ++mt)
      af[mt] = ldsv(As + (wm + mt * 16 + l15) * 32 + qd * 8);
#pragma unroll
    for (int nt = 0; nt < 4; ++nt)
      bfr[nt] = ldsv(Bs + (wn + nt * 16 + l15) * 32 + qd * 8);
#pragma unroll
    for (int mt = 0; mt < 4; ++mt)
#pragma unroll
      for (int nt = 0; nt < 4; ++nt)
        acc[mt][nt] = __builtin_amdgcn_mfma_f32_16x16x32_bf16(af[mt], bfr[nt], acc[mt][nt], 0, 0, 0);
  }

#pragma unroll
  for (int mt = 0; mt < 4; ++mt) {
#pragma unroll
    for (int nt = 0; nt < 4; ++nt) {
      const int col   = n0 + wn + nt * 16 + l15;
      const int rbase = m0 + wm + mt * 16 + qd * 4;
      const float bv = bias[col];
#pragma unroll
      for (int r = 0; r < 4; ++r)
        outf[(size_t)(rbase + r) * EDIM + col] = acc[mt][nt][r] + bv;
    }
  }
}

// ---------------- flash attention (S^T formulation, no-max softmax) ----------------
// Q pre-scaled by scale*log2(e) in its GEMM epilogue, so p = exp2(st) directly.
// Qs (16KB) is aliased as the per-wave P staging buffer after the qf load.
// Grid: 1024 blocks, swizzled so all 16 q-tiles of one (b,h) share an XCD.
__global__ __launch_bounds__(256)
void attn_kernel(const unsigned short* __restrict__ Q,
                 const unsigned short* __restrict__ K,
                 const unsigned short* __restrict__ VT,
                 unsigned short* __restrict__ O)
{
  __shared__ __align__(16) unsigned short Qs[128 * 64];  // aliased as Ps after qf load
  __shared__ __align__(16) unsigned short Ks[64 * 64];
  __shared__ __align__(16) unsigned short Vs[64 * 64];
  unsigned short* Ps = Qs;  // per-wave [qrow 32][j 64], wave wv owns rows [wv*32, wv*32+32)

  const int t   = threadIdx.x;
  const int wv  = t >> 6;
  const int ln  = t & 63;
  const int l15 = ln & 15;
  const int qd  = ln >> 4;

  // XCD-locality decode: L = bh_hi*128 + qt*8 + bh_lo
  const int L      = blockIdx.x;
  const int bh     = ((L >> 7) << 3) | (L & 7);
  const int qt     = (L >> 3) & 15;
  const int q0     = qt * 128;
  const int b      = bh >> 4;      // bh = b*HEADS + h
  const int h      = bh & 15;

  const unsigned short* Qp = Q + (size_t)b * SEQN * EDIM + h * DIMH;
  const unsigned short* Kp = K + (size_t)b * SEQM * EDIM + h * DIMH;
  const unsigned short* Vp = VT + ((size_t)bh) * DIMH * SEQM;

  // stage Q tile (128x64), XOR-swizzled 16B chunks
#pragma unroll
  for (int l = 0; l < 4; ++l) {
    const int i = l * 256 + wv * 64 + ln;     // 0..1023
    const int row = i >> 3, ch = i & 7;
    const int gch = ch ^ (row & 7);
    async16(Qp + (size_t)(q0 + row) * EDIM + gch * 8, Qs + i * 8);
  }
  __syncthreads();

  // Q fragments (used as MFMA B-operand -> acts as Q^T); frees Qs for reuse as Ps
  bf16x8 qf[2][2];
#pragma unroll
  for (int qc = 0; qc < 2; ++qc) {
    const int row = wv * 32 + qc * 16 + l15;
#pragma unroll
    for (int ks = 0; ks < 2; ++ks) {
      const int c = (ks * 4 + qd) ^ (row & 7);
      qf[qc][ks] = ldsv(Qs + row * 64 + c * 8);
    }
  }

  // strength-reduced staging pointers (advance by fixed strides per j-tile)
  const unsigned short* kg[2];
  const unsigned short* vg[2];
  unsigned short* kls[2];
  unsigned short* vls[2];
#pragma unroll
  for (int l = 0; l < 2; ++l) {
    const int i = l * 256 + wv * 64 + ln;     // 0..511
    const int row = i >> 3, ch = i & 7;
    const int gch = ch ^ (row & 7);
    kg[l] = Kp + (size_t)row * EDIM + gch * 8;
    vg[l] = Vp + (size_t)row * SEQM + gch * 8;
    kls[l] = Ks + i * 8;
    vls[l] = Vs + i * 8;
  }

  const f32x4 vzero = {0.f, 0.f, 0.f, 0.f};
  f32x4 o_acc[2][4];
#pragma unroll
  for (int qc = 0; qc < 2; ++qc)
#pragma unroll
    for (int dt = 0; dt < 4; ++dt) o_acc[qc][dt] = vzero;

  float2 rs2[2] = {{0.f, 0.f}, {0.f, 0.f}};  // packed partial row-sums

  unsigned short* Pw = Ps + wv * 2048;  // wave-private P region (aliases own Q rows)

  for (int j0 = 0; j0 < SEQM; j0 += 64) {
    __syncthreads();
    async16(kg[0], kls[0]);
    async16(kg[1], kls[1]);
    async16(vg[0], vls[0]);
    async16(vg[1], vls[1]);
    kg[0] += 64 * EDIM; kg[1] += 64 * EDIM;
    vg[0] += 64;        vg[1] += 64;
    __syncthreads();

    // S^T = K * Q^T   (C-layout: row = j = qd*4+r, col = qrow = l15)
    f32x4 st[2][4];
#pragma unroll
    for (int qc = 0; qc < 2; ++qc)
#pragma unroll
      for (int jt = 0; jt < 4; ++jt) st[qc][jt] = vzero;

#pragma unroll
    for (int jt = 0; jt < 4; ++jt) {
      const int rowj = jt * 16 + l15;
#pragma unroll
      for (int ks = 0; ks < 2; ++ks) {
        const int c = (ks * 4 + qd) ^ (rowj & 7);
        const bf16x8 kf = ldsv(Ks + rowj * 64 + c * 8);
        st[0][jt] = __builtin_amdgcn_mfma_f32_16x16x32_bf16(kf, qf[0][ks], st[0][jt], 0, 0, 0);
        st[1][jt] = __builtin_amdgcn_mfma_f32_16x16x32_bf16(kf, qf[1][ks], st[1][jt], 0, 0, 0);
      }
    }

    // exp + pack + P write (all in-lane; j-consecutive regs; no bias needed)
#pragma unroll
    for (int qc = 0; qc < 2; ++qc) {
      unsigned short* prow = Pw + (qc * 16 + l15) * 64;
#pragma unroll
      for (int jt = 0; jt < 4; ++jt) {
        float p0 = fexp2(st[qc][jt][0]);
        float p1 = fexp2(st[qc][jt][1]);
        float p2 = fexp2(st[qc][jt][2]);
        float p3 = fexp2(st[qc][jt][3]);
        rs2[qc].x += p0 + p2;   // packed adds (v_pk_add_f32-friendly)
        rs2[qc].y += p1 + p3;
        uint2 dw;
        dw.x = pk_bf16(p0, p1);
        dw.y = pk_bf16(p2, p3);
        const int c = (jt * 4 + qd) ^ l15;       // b64-chunk swizzle (bank-uniform)
        *(uint2*)(prow + c * 4) = dw;
      }
    }
    asm volatile("" ::: "memory");  // keep Ps writes before reads (same-wave DS in-order)

    // O += P * V
#pragma unroll
    for (int ks2 = 0; ks2 < 2; ++ks2) {
      bf16x8 pf[2];
#pragma unroll
      for (int qc = 0; qc < 2; ++qc) {
        const unsigned short* prow = Pw + (qc * 16 + l15) * 64;
        const int c0 = ks2 * 8 + qd * 2;
        uint2 lo = *(const uint2*)(prow + ((c0)     ^ l15) * 4);
        uint2 hi = *(const uint2*)(prow + ((c0 + 1) ^ l15) * 4);
        union { uint32_t u[4]; bf16x8 v; } cc;
        cc.u[0] = lo.x; cc.u[1] = lo.y; cc.u[2] = hi.x; cc.u[3] = hi.y;
        pf[qc] = cc.v;
      }
#pragma unroll
      for (int dt = 0; dt < 4; ++dt) {
        const int rowd = dt * 16 + l15;
        const int c = (ks2 * 4 + qd) ^ (rowd & 7);
        const bf16x8 vf = ldsv(Vs + rowd * 64 + c * 8);
        o_acc[0][dt] = __builtin_amdgcn_mfma_f32_16x16x32_bf16(pf[0], vf, o_acc[0][dt], 0, 0, 0);
        o_acc[1][dt] = __builtin_amdgcn_mfma_f32_16x16x32_bf16(pf[1], vf, o_acc[1][dt], 0, 0, 0);
      }
    }
  }

  // final l reduction: per-lane partial -> full sum per qrow (over qd groups)
  float rsum[2];
#pragma unroll
  for (int qc = 0; qc < 2; ++qc) {
    float r = rs2[qc].x + rs2[qc].y;
    r += __shfl_xor(r, 16);
    r += __shfl_xor(r, 32);
    rsum[qc] = r;  // every lane now has l for qrow = qc*16 + l15
  }

  // normalize + write O (bf16 row-major)
  unsigned short* Op = O + (size_t)b * SEQN * EDIM + h * DIMH;
#pragma unroll
  for (int qc = 0; qc < 2; ++qc) {
    float inv[4];
#pragma unroll
    for (int r = 0; r < 4; ++r)
      inv[r] = 1.0f / __shfl(rsum[qc], qd * 4 + r);  // l for qrow = qc*16 + qd*4 + r
#pragma unroll
    for (int dt = 0; dt < 4; ++dt) {
      const int col = dt * 16 + l15;
#pragma unroll
      for (int r = 0; r < 4; ++r) {
        const int row = q0 + wv * 32 + qc * 16 + qd * 4 + r;
        Op[(size_t)row * EDIM + col] = f2bf(o_acc[qc][dt][r] * inv[r]);
      }
    }
  }
}

// ---------------- launch ----------------
extern "C" void kernel_launch(void* const* d_in, const int* in_sizes, int n_in,
                              void* d_out, int out_size, void* d_ws, size_t ws_size,
                              hipStream_t stream) {
  const float* x   = (const float*)d_in[0];
  const float* ctx = (const float*)d_in[1];
  const float* Wq  = (const float*)d_in[2];
  const float* Wk  = (const float*)d_in[3];
  const float* Wv  = (const float*)d_in[4];
  const float* Wo  = (const float*)d_in[5];
  const float* bo  = (const float*)d_in[6];
  float* out = (float*)d_out;

  char* ws = (char*)d_ws;
  const size_t SZ_X = (size_t)NB * SEQN * EDIM * 2;  // 16 MiB (bf16 activations)
  const size_t SZ_W = (size_t)EDIM * KD * 2;         // 2 MiB  (bf16 weights)
  unsigned short* xb  = (unsigned short*)(ws);
  unsigned short* cb  = (unsigned short*)(ws + SZ_X);
  unsigned short* wqb = (unsigned short*)(ws + 2 * SZ_X);
  unsigned short* wkb = (unsigned short*)(ws + 2 * SZ_X + SZ_W);
  unsigned short* wvb = (unsigned short*)(ws + 2 * SZ_X + 2 * SZ_W);
  unsigned short* wob = (unsigned short*)(ws + 2 * SZ_X + 3 * SZ_W);
  unsigned short* Qb  = (unsigned short*)(ws + 2 * SZ_X + 4 * SZ_W);
  unsigned short* Kb  = (unsigned short*)(ws + 3 * SZ_X + 4 * SZ_W);
  unsigned short* Vtb = (unsigned short*)(ws + 4 * SZ_X + 4 * SZ_W);
  unsigned short* Ob  = (unsigned short*)(ws + 5 * SZ_X + 4 * SZ_W);

  const int n4x = (NB * SEQN * EDIM) / 4;   // 2097152 float4 groups per activation
  const int n4w = (EDIM * KD) / 4;          // 262144 per weight
  const int bpx = n4x / 256;                // 8192 blocks per segment
  const int bpw = n4w / 256;                // 1024 blocks per segment
  cvt2<<<2 * bpx, 256, 0, stream>>>((const float4*)x, (const float4*)ctx,
                                    (ushort4*)xb, (ushort4*)cb, bpx);
  cvt4<<<4 * bpw, 256, 0, stream>>>((const float4*)Wq, (const float4*)Wk,
                                    (const float4*)Wv, (const float4*)Wo,
                                    (ushort4*)wqb, (ushort4*)wkb,
                                    (ushort4*)wvb, (ushort4*)wob, bpw);

  const float SCL2E = 0.125f * 1.4426950408889634f;  // dim_head^-0.5 * log2(e)
  const dim3 blk(256);

  gemm_qkv<<<dim3(EDIM / 128, (NB * SEQN) / 128, 3), blk, 0, stream>>>(
      xb, cb, wqb, wkb, wvb, Qb, Kb, Vtb, SCL2E);

  attn_kernel<<<dim3(1024), blk, 0, stream>>>(Qb, Kb, Vtb, Ob);

  gemm_out<<<dim3(EDIM / 128, (NB * SEQN) / 128), blk, 0, stream>>>(Ob, wob, out, bo);
}

// Round 6
// 328.952 us; speedup vs baseline: 1.0501x; 1.0501x over previous
//
#include <hip/hip_runtime.h>
#include <hip/hip_bf16.h>
#include <stdint.h>

#define HEADS 16
#define DIMH  64
#define SEQN  2048
#define SEQM  2048
#define NB    4
#define EDIM  1024
#define KD    1024

using bf16_t = __bf16;
using bf16x8 = __attribute__((ext_vector_type(8))) bf16_t;
using f32x4  = __attribute__((ext_vector_type(4))) float;

__device__ __forceinline__ unsigned short f2bf(float f) {
  union { float f; uint32_t u; } v; v.f = f;
  uint32_t u = v.u;
  u += 0x7fffu + ((u >> 16) & 1u);   // round-to-nearest-even
  return (unsigned short)(u >> 16);
}

#if __has_builtin(__builtin_amdgcn_cvt_pk_bf16_f32)
typedef __bf16 bf16x2_t __attribute__((ext_vector_type(2)));
__device__ __forceinline__ uint32_t pk_bf16(float a, float b) {
  union { bf16x2_t v; uint32_t u; } c;
  c.v = __builtin_amdgcn_cvt_pk_bf16_f32(a, b);  // low = a, high = b
  return c.u;
}
#else
__device__ __forceinline__ uint32_t pk_bf16(float a, float b) {
  union { __hip_bfloat162 v; uint32_t u; } c;
  c.v = __float22bfloat162_rn(float2{a, b});
  return c.u;
}
#endif

#if __has_builtin(__builtin_amdgcn_exp2f)
__device__ __forceinline__ float fexp2(float x) { return __builtin_amdgcn_exp2f(x); }
#else
__device__ __forceinline__ float fexp2(float x) { return exp2f(x); }
#endif

__device__ __forceinline__ void async16(const void* g, void* l) {
  __builtin_amdgcn_global_load_lds(
      (__attribute__((address_space(1))) void*)(g),
      (__attribute__((address_space(3))) void*)(l), 16, 0, 0);
}

__device__ __forceinline__ bf16x8 ldsv(const unsigned short* p) {
  return *(const bf16x8*)p;
}

// ---------------- fp32 -> bf16 converts (fused, 2 launches) ----------------
__global__ __launch_bounds__(256)
void cvt2(const float4* __restrict__ a, const float4* __restrict__ b,
          ushort4* __restrict__ oa, ushort4* __restrict__ ob, int blocks_per_seg) {
  const int seg = blockIdx.x / blocks_per_seg;
  const int i = (blockIdx.x - seg * blocks_per_seg) * 256 + threadIdx.x;
  const float4* in = seg ? b : a;
  ushort4* out = seg ? ob : oa;
  float4 v = in[i];
  ushort4 o;
  o.x = f2bf(v.x); o.y = f2bf(v.y); o.z = f2bf(v.z); o.w = f2bf(v.w);
  out[i] = o;
}

__global__ __launch_bounds__(256)
void cvt4(const float4* __restrict__ a, const float4* __restrict__ b,
          const float4* __restrict__ c, const float4* __restrict__ d,
          ushort4* __restrict__ oa, ushort4* __restrict__ ob,
          ushort4* __restrict__ oc, ushort4* __restrict__ od, int blocks_per_seg) {
  const int seg = blockIdx.x / blocks_per_seg;
  const int i = (blockIdx.x - seg * blocks_per_seg) * 256 + threadIdx.x;
  const float4* in = (seg == 0) ? a : (seg == 1) ? b : (seg == 2) ? c : d;
  ushort4* out = (seg == 0) ? oa : (seg == 1) ? ob : (seg == 2) ? oc : od;
  float4 v = in[i];
  ushort4 o;
  o.x = f2bf(v.x); o.y = f2bf(v.y); o.z = f2bf(v.z); o.w = f2bf(v.w);
  out[i] = o;
}

// ---------------- fused Q/K/V projection GEMM, XCD-swizzled ----------------
// 1-D grid of 1536 blocks: L = xcd | n<<3 | mq<<6 | z<<9, m = mq*8 + xcd.
// -> all 8 n-blocks of one (m,z) A-panel land on ONE XCD (A fetched from HBM
//    once, then L2-resident), and each XCD runs one z at a time so the live
//    W working set stays ~2MB (< 4MB XCD L2).
// z: 0 -> Q = x*Wq^T (bf16, pre-scaled by scale*log2e)
//    1 -> K = ctx*Wk^T (bf16)
//    2 -> V^T = (ctx*Wv^T)^T as [b][h][d][m] bf16
__global__ __launch_bounds__(256)
void gemm_qkv(const unsigned short* __restrict__ xb,
              const unsigned short* __restrict__ cb,
              const unsigned short* __restrict__ wqb,
              const unsigned short* __restrict__ wkb,
              const unsigned short* __restrict__ wvb,
              unsigned short* __restrict__ Qb,
              unsigned short* __restrict__ Kb,
              unsigned short* __restrict__ Vtb,
              float qscale)
{
  __shared__ __align__(16) unsigned short As[128 * 32];
  __shared__ __align__(16) unsigned short Bs[128 * 32];
  const int t   = threadIdx.x;
  const int wv  = t >> 6;
  const int ln  = t & 63;
  const int l15 = ln & 15;
  const int qd  = ln >> 4;

  const int L   = blockIdx.x;
  const int xcd = L & 7;
  const int n0  = ((L >> 3) & 7) * 128;
  const int mq  = (L >> 6) & 7;
  const int z   = L >> 9;                 // 0..2
  const int m0  = (mq * 8 + xcd) * 128;

  const int wm  = (wv >> 1) * 64;
  const int wn  = (wv & 1) * 64;

  const unsigned short* A = (z == 0) ? xb : cb;
  const unsigned short* W = (z == 0) ? wqb : (z == 1) ? wkb : wvb;

  const f32x4 vzero = {0.f, 0.f, 0.f, 0.f};
  f32x4 acc[4][4];
#pragma unroll
  for (int i = 0; i < 4; ++i)
#pragma unroll
    for (int j = 0; j < 4; ++j) acc[i][j] = vzero;

  for (int k0 = 0; k0 < KD; k0 += 32) {
    __syncthreads();
#pragma unroll
    for (int l = 0; l < 2; ++l) {
      const int i = l * 256 + wv * 64 + ln;   // 0..511
      const int row = i >> 2, ch = i & 3;     // 128 rows x 4 chunks(16B)
      async16(A + (size_t)(m0 + row) * KD + k0 + ch * 8, As + i * 8);
      async16(W + (size_t)(n0 + row) * KD + k0 + ch * 8, Bs + i * 8);
    }
    __syncthreads();
    bf16x8 af[4], bfr[4];
#pragma unroll
    for (int mt = 0; mt < 4; ++mt)
      af[mt] = ldsv(As + (wm + mt * 16 + l15) * 32 + qd * 8);
#pragma unroll
    for (int nt = 0; nt < 4; ++nt)
      bfr[nt] = ldsv(Bs + (wn + nt * 16 + l15) * 32 + qd * 8);
#pragma unroll
    for (int mt = 0; mt < 4; ++mt)
#pragma unroll
      for (int nt = 0; nt < 4; ++nt)
        acc[mt][nt] = __builtin_amdgcn_mfma_f32_16x16x32_bf16(af[mt], bfr[nt], acc[mt][nt], 0, 0, 0);
  }

  // epilogue: C/D layout col=l15, row=qd*4+r
  const float scale = (z == 0) ? qscale : 1.0f;
#pragma unroll
  for (int mt = 0; mt < 4; ++mt) {
#pragma unroll
    for (int nt = 0; nt < 4; ++nt) {
      const int col   = n0 + wn + nt * 16 + l15;
      const int rbase = m0 + wm + mt * 16 + qd * 4;
      if (z < 2) {
        unsigned short* outb = (z == 0) ? Qb : Kb;
#pragma unroll
        for (int r = 0; r < 4; ++r)
          outb[(size_t)(rbase + r) * EDIM + col] = f2bf(acc[mt][nt][r] * scale);
      } else {
        const int b = rbase >> 11, m = rbase & 2047;
        const int h = col >> 6,   d = col & 63;
        ushort4 o;
        o.x = f2bf(acc[mt][nt][0]); o.y = f2bf(acc[mt][nt][1]);
        o.z = f2bf(acc[mt][nt][2]); o.w = f2bf(acc[mt][nt][3]);
        *(ushort4*)(Vtb + ((size_t)(b * HEADS + h) * DIMH + d) * SEQM + m) = o;
      }
    }
  }
}

// ---------------- output projection GEMM (fp32 out + bias), XCD-swizzled ----------------
// 1-D grid of 512 blocks: L = xcd | n<<3 | mq<<6, m = mq*8 + xcd.
__global__ __launch_bounds__(256)
void gemm_out(const unsigned short* __restrict__ A,
              const unsigned short* __restrict__ W,
              float* __restrict__ outf,
              const float* __restrict__ bias)
{
  __shared__ __align__(16) unsigned short As[128 * 32];
  __shared__ __align__(16) unsigned short Bs[128 * 32];
  const int t   = threadIdx.x;
  const int wv  = t >> 6;
  const int ln  = t & 63;
  const int l15 = ln & 15;
  const int qd  = ln >> 4;

  const int L   = blockIdx.x;
  const int xcd = L & 7;
  const int n0  = ((L >> 3) & 7) * 128;
  const int mq  = L >> 6;                 // 0..7
  const int m0  = (mq * 8 + xcd) * 128;

  const int wm  = (wv >> 1) * 64;
  const int wn  = (wv & 1) * 64;

  const f32x4 vzero = {0.f, 0.f, 0.f, 0.f};
  f32x4 acc[4][4];
#pragma unroll
  for (int i = 0; i < 4; ++i)
#pragma unroll
    for (int j = 0; j < 4; ++j) acc[i][j] = vzero;

  for (int k0 = 0; k0 < KD; k0 += 32) {
    __syncthreads();
#pragma unroll
    for (int l = 0; l < 2; ++l) {
      const int i = l * 256 + wv * 64 + ln;
      const int row = i >> 2, ch = i & 3;
      async16(A + (size_t)(m0 + row) * KD + k0 + ch * 8, As + i * 8);
      async16(W + (size_t)(n0 + row) * KD + k0 + ch * 8, Bs + i * 8);
    }
    __syncthreads();
    bf16x8 af[4], bfr[4];
#pragma unroll
    for (int mt = 0; mt < 4; ++mt)
      af[mt] = ldsv(As + (wm + mt * 16 + l15) * 32 + qd * 8);
#pragma unroll
    for (int nt = 0; nt < 4; ++nt)
      bfr[nt] = ldsv(Bs + (wn + nt * 16 + l15) * 32 + qd * 8);
#pragma unroll
    for (int mt = 0; mt < 4; ++mt)
#pragma unroll
      for (int nt = 0; nt < 4; ++nt)
        acc[mt][nt] = __builtin_amdgcn_mfma_f32_16x16x32_bf16(af[mt], bfr[nt], acc[mt][nt], 0, 0, 0);
  }

#pragma unroll
  for (int mt = 0; mt < 4; ++mt) {
#pragma unroll
    for (int nt = 0; nt < 4; ++nt) {
      const int col   = n0 + wn + nt * 16 + l15;
      const int rbase = m0 + wm + mt * 16 + qd * 4;
      const float bv = bias[col];
#pragma unroll
      for (int r = 0; r < 4; ++r)
        outf[(size_t)(rbase + r) * EDIM + col] = acc[mt][nt][r] + bv;
    }
  }
}

// ---------------- flash attention (r4 version, verbatim) ----------------
// S^T formulation, no-max softmax (Q pre-scaled by scale*log2e), Qs aliased
// as per-wave P buffer, XCD-swizzled grid.
__global__ __launch_bounds__(256)
void attn_kernel(const unsigned short* __restrict__ Q,
                 const unsigned short* __restrict__ K,
                 const unsigned short* __restrict__ VT,
                 unsigned short* __restrict__ O)
{
  __shared__ __align__(16) unsigned short Qs[128 * 64];  // aliased as Ps after qf load
  __shared__ __align__(16) unsigned short Ks[64 * 64];
  __shared__ __align__(16) unsigned short Vs[64 * 64];
  unsigned short* Ps = Qs;  // per-wave [qrow 32][j 64], wave wv owns rows [wv*32, wv*32+32)

  const int t   = threadIdx.x;
  const int wv  = t >> 6;
  const int ln  = t & 63;
  const int l15 = ln & 15;
  const int qd  = ln >> 4;

  // XCD-locality decode: L = bh_hi*128 + qt*8 + bh_lo
  const int L      = blockIdx.x;
  const int bh     = ((L >> 7) << 3) | (L & 7);
  const int qt     = (L >> 3) & 15;
  const int q0     = qt * 128;
  const int b      = bh >> 4;      // bh = b*HEADS + h
  const int h      = bh & 15;

  const unsigned short* Qp = Q + (size_t)b * SEQN * EDIM + h * DIMH;
  const unsigned short* Kp = K + (size_t)b * SEQM * EDIM + h * DIMH;
  const unsigned short* Vp = VT + ((size_t)bh) * DIMH * SEQM;

  // stage Q tile (128x64), XOR-swizzled 16B chunks
#pragma unroll
  for (int l = 0; l < 4; ++l) {
    const int i = l * 256 + wv * 64 + ln;     // 0..1023
    const int row = i >> 3, ch = i & 7;
    const int gch = ch ^ (row & 7);
    async16(Qp + (size_t)(q0 + row) * EDIM + gch * 8, Qs + i * 8);
  }
  __syncthreads();

  // Q fragments (used as MFMA B-operand -> acts as Q^T); frees Qs for reuse as Ps
  bf16x8 qf[2][2];
#pragma unroll
  for (int qc = 0; qc < 2; ++qc) {
    const int row = wv * 32 + qc * 16 + l15;
#pragma unroll
    for (int ks = 0; ks < 2; ++ks) {
      const int c = (ks * 4 + qd) ^ (row & 7);
      qf[qc][ks] = ldsv(Qs + row * 64 + c * 8);
    }
  }

  const f32x4 vzero = {0.f, 0.f, 0.f, 0.f};
  f32x4 o_acc[2][4];
#pragma unroll
  for (int qc = 0; qc < 2; ++qc)
#pragma unroll
    for (int dt = 0; dt < 4; ++dt) o_acc[qc][dt] = vzero;

  float rsum[2] = {0.f, 0.f};

  unsigned short* Pw = Ps + wv * 2048;  // wave-private P region (aliases own Q rows)

  for (int j0 = 0; j0 < SEQM; j0 += 64) {
    __syncthreads();
#pragma unroll
    for (int l = 0; l < 2; ++l) {
      const int i = l * 256 + wv * 64 + ln;   // 0..511
      const int row = i >> 3, ch = i & 7;
      const int gch = ch ^ (row & 7);
      async16(Kp + (size_t)(j0 + row) * EDIM + gch * 8, Ks + i * 8);
      async16(Vp + (size_t)row * SEQM + j0 + gch * 8, Vs + i * 8);
    }
    __syncthreads();

    // S^T = K * Q^T   (C-layout: row = j = qd*4+r, col = qrow = l15)
    f32x4 st[2][4];
#pragma unroll
    for (int qc = 0; qc < 2; ++qc)
#pragma unroll
      for (int jt = 0; jt < 4; ++jt) st[qc][jt] = vzero;

#pragma unroll
    for (int jt = 0; jt < 4; ++jt) {
      const int rowj = jt * 16 + l15;
#pragma unroll
      for (int ks = 0; ks < 2; ++ks) {
        const int c = (ks * 4 + qd) ^ (rowj & 7);
        const bf16x8 kf = ldsv(Ks + rowj * 64 + c * 8);
        st[0][jt] = __builtin_amdgcn_mfma_f32_16x16x32_bf16(kf, qf[0][ks], st[0][jt], 0, 0, 0);
        st[1][jt] = __builtin_amdgcn_mfma_f32_16x16x32_bf16(kf, qf[1][ks], st[1][jt], 0, 0, 0);
      }
    }

    // exp + pack + P write (all in-lane; j-consecutive regs; no bias needed)
#pragma unroll
    for (int qc = 0; qc < 2; ++qc) {
      unsigned short* prow = Pw + (qc * 16 + l15) * 64;
#pragma unroll
      for (int jt = 0; jt < 4; ++jt) {
        float p0 = fexp2(st[qc][jt][0]);
        float p1 = fexp2(st[qc][jt][1]);
        float p2 = fexp2(st[qc][jt][2]);
        float p3 = fexp2(st[qc][jt][3]);
        rsum[qc] += (p0 + p1) + (p2 + p3);
        uint2 dw;
        dw.x = pk_bf16(p0, p1);
        dw.y = pk_bf16(p2, p3);
        const int c = (jt * 4 + qd) ^ l15;       // b64-chunk swizzle (bank-uniform)
        *(uint2*)(prow + c * 4) = dw;
      }
    }
    asm volatile("" ::: "memory");  // keep Ps writes before reads (same-wave DS in-order)

    // O += P * V
#pragma unroll
    for (int ks2 = 0; ks2 < 2; ++ks2) {
      bf16x8 pf[2];
#pragma unroll
      for (int qc = 0; qc < 2; ++qc) {
        const unsigned short* prow = Pw + (qc * 16 + l15) * 64;
        const int c0 = ks2 * 8 + qd * 2;
        uint2 lo = *(const uint2*)(prow + ((c0)     ^ l15) * 4);
        uint2 hi = *(const uint2*)(prow + ((c0 + 1) ^ l15) * 4);
        union { uint32_t u[4]; bf16x8 v; } cc;
        cc.u[0] = lo.x; cc.u[1] = lo.y; cc.u[2] = hi.x; cc.u[3] = hi.y;
        pf[qc] = cc.v;
      }
#pragma unroll
      for (int dt = 0; dt < 4; ++dt) {
        const int rowd = dt * 16 + l15;
        const int c = (ks2 * 4 + qd) ^ (rowd & 7);
        const bf16x8 vf = ldsv(Vs + rowd * 64 + c * 8);
        o_acc[0][dt] = __builtin_amdgcn_mfma_f32_16x16x32_bf16(pf[0], vf, o_acc[0][dt], 0, 0, 0);
        o_acc[1][dt] = __builtin_amdgcn_mfma_f32_16x16x32_bf16(pf[1], vf, o_acc[1][dt], 0, 0, 0);
      }
    }
  }

  // final l reduction: per-lane partial -> full sum per qrow (over qd groups)
#pragma unroll
  for (int qc = 0; qc < 2; ++qc) {
    float r = rsum[qc];
    r += __shfl_xor(r, 16);
    r += __shfl_xor(r, 32);
    rsum[qc] = r;  // every lane now has l for qrow = qc*16 + l15
  }

  // normalize + write O (bf16 row-major)
  unsigned short* Op = O + (size_t)b * SEQN * EDIM + h * DIMH;
#pragma unroll
  for (int qc = 0; qc < 2; ++qc) {
    float inv[4];
#pragma unroll
    for (int r = 0; r < 4; ++r)
      inv[r] = 1.0f / __shfl(rsum[qc], qd * 4 + r);  // l for qrow = qc*16 + qd*4 + r
#pragma unroll
    for (int dt = 0; dt < 4; ++dt) {
      const int col = dt * 16 + l15;
#pragma unroll
      for (int r = 0; r < 4; ++r) {
        const int row = q0 + wv * 32 + qc * 16 + qd * 4 + r;
        Op[(size_t)row * EDIM + col] = f2bf(o_acc[qc][dt][r] * inv[r]);
      }
    }
  }
}

// ---------------- launch ----------------
extern "C" void kernel_launch(void* const* d_in, const int* in_sizes, int n_in,
                              void* d_out, int out_size, void* d_ws, size_t ws_size,
                              hipStream_t stream) {
  const float* x   = (const float*)d_in[0];
  const float* ctx = (const float*)d_in[1];
  const float* Wq  = (const float*)d_in[2];
  const float* Wk  = (const float*)d_in[3];
  const float* Wv  = (const float*)d_in[4];
  const float* Wo  = (const float*)d_in[5];
  const float* bo  = (const float*)d_in[6];
  float* out = (float*)d_out;

  char* ws = (char*)d_ws;
  const size_t SZ_X = (size_t)NB * SEQN * EDIM * 2;  // 16 MiB (bf16 activations)
  const size_t SZ_W = (size_t)EDIM * KD * 2;         // 2 MiB  (bf16 weights)
  unsigned short* xb  = (unsigned short*)(ws);
  unsigned short* cb  = (unsigned short*)(ws + SZ_X);
  unsigned short* wqb = (unsigned short*)(ws + 2 * SZ_X);
  unsigned short* wkb = (unsigned short*)(ws + 2 * SZ_X + SZ_W);
  unsigned short* wvb = (unsigned short*)(ws + 2 * SZ_X + 2 * SZ_W);
  unsigned short* wob = (unsigned short*)(ws + 2 * SZ_X + 3 * SZ_W);
  unsigned short* Qb  = (unsigned short*)(ws + 2 * SZ_X + 4 * SZ_W);
  unsigned short* Kb  = (unsigned short*)(ws + 3 * SZ_X + 4 * SZ_W);
  unsigned short* Vtb = (unsigned short*)(ws + 4 * SZ_X + 4 * SZ_W);
  unsigned short* Ob  = (unsigned short*)(ws + 5 * SZ_X + 4 * SZ_W);

  const int n4x = (NB * SEQN * EDIM) / 4;   // 2097152 float4 groups per activation
  const int n4w = (EDIM * KD) / 4;          // 262144 per weight
  const int bpx = n4x / 256;                // 8192 blocks per segment
  const int bpw = n4w / 256;                // 1024 blocks per segment
  cvt2<<<2 * bpx, 256, 0, stream>>>((const float4*)x, (const float4*)ctx,
                                    (ushort4*)xb, (ushort4*)cb, bpx);
  cvt4<<<4 * bpw, 256, 0, stream>>>((const float4*)Wq, (const float4*)Wk,
                                    (const float4*)Wv, (const float4*)Wo,
                                    (ushort4*)wqb, (ushort4*)wkb,
                                    (ushort4*)wvb, (ushort4*)wob, bpw);

  const float SCL2E = 0.125f * 1.4426950408889634f;  // dim_head^-0.5 * log2(e)
  const dim3 blk(256);

  gemm_qkv<<<dim3(1536), blk, 0, stream>>>(
      xb, cb, wqb, wkb, wvb, Qb, Kb, Vtb, SCL2E);

  attn_kernel<<<dim3(1024), blk, 0, stream>>>(Qb, Kb, Vtb, Ob);

  gemm_out<<<dim3(512), blk, 0, stream>>>(Ob, wob, out, bo);
}

// Round 7
// 315.479 us; speedup vs baseline: 1.0949x; 1.0427x over previous
//
#include <hip/hip_runtime.h>
#include <hip/hip_bf16.h>
#include <stdint.h>

#define HEADS 16
#define DIMH  64
#define SEQN  2048
#define SEQM  2048
#define NB    4
#define EDIM  1024
#define KD    1024

using bf16_t = __bf16;
using bf16x8 = __attribute__((ext_vector_type(8))) bf16_t;
using f32x4  = __attribute__((ext_vector_type(4))) float;

__device__ __forceinline__ unsigned short f2bf(float f) {
  union { float f; uint32_t u; } v; v.f = f;
  uint32_t u = v.u;
  u += 0x7fffu + ((u >> 16) & 1u);   // round-to-nearest-even
  return (unsigned short)(u >> 16);
}

#if __has_builtin(__builtin_amdgcn_cvt_pk_bf16_f32)
typedef __bf16 bf16x2_t __attribute__((ext_vector_type(2)));
__device__ __forceinline__ uint32_t pk_bf16(float a, float b) {
  union { bf16x2_t v; uint32_t u; } c;
  c.v = __builtin_amdgcn_cvt_pk_bf16_f32(a, b);  // low = a, high = b
  return c.u;
}
#else
__device__ __forceinline__ uint32_t pk_bf16(float a, float b) {
  union { __hip_bfloat162 v; uint32_t u; } c;
  c.v = __float22bfloat162_rn(float2{a, b});
  return c.u;
}
#endif

#if __has_builtin(__builtin_amdgcn_exp2f)
__device__ __forceinline__ float fexp2(float x) { return __builtin_amdgcn_exp2f(x); }
#else
__device__ __forceinline__ float fexp2(float x) { return exp2f(x); }
#endif

__device__ __forceinline__ void async16(const void* g, void* l) {
  __builtin_amdgcn_global_load_lds(
      (__attribute__((address_space(1))) void*)(g),
      (__attribute__((address_space(3))) void*)(l), 16, 0, 0);
}

__device__ __forceinline__ bf16x8 ldsv(const unsigned short* p) {
  return *(const bf16x8*)p;
}

// ---------------- fp32 -> bf16 convert (single launch, 6 segments) ----------------
__global__ __launch_bounds__(256)
void cvt_all(const float4* __restrict__ x,  const float4* __restrict__ ctx,
             const float4* __restrict__ wq, const float4* __restrict__ wk,
             const float4* __restrict__ wv, const float4* __restrict__ wo,
             ushort4* __restrict__ xb,  ushort4* __restrict__ cb,
             ushort4* __restrict__ wqb, ushort4* __restrict__ wkb,
             ushort4* __restrict__ wvb, ushort4* __restrict__ wob) {
  const int bid = blockIdx.x;
  const float4* in; ushort4* out; int i0;
  if (bid < 8192)       { in = x;   out = xb;  i0 = bid; }
  else if (bid < 16384) { in = ctx; out = cb;  i0 = bid - 8192; }
  else if (bid < 17408) { in = wq;  out = wqb; i0 = bid - 16384; }
  else if (bid < 18432) { in = wk;  out = wkb; i0 = bid - 17408; }
  else if (bid < 19456) { in = wv;  out = wvb; i0 = bid - 18432; }
  else                  { in = wo;  out = wob; i0 = bid - 19456; }
  const int i = i0 * 256 + threadIdx.x;
  float4 v = in[i];
  ushort4 o;
  o.x = f2bf(v.x); o.y = f2bf(v.y); o.z = f2bf(v.z); o.w = f2bf(v.w);
  out[i] = o;
}

// ---------------- fused Q/K/V projection GEMM, XCD-swizzled, BK=64 ----------------
// Grid 1536: L = xcd | n<<3 | mq<<6 | z<<9, m = mq*8 + xcd (A-panel locality per XCD).
// BK=64, 64-short LDS rows with XOR-8 chunk swizzle (attn-style): conflict-free
// ds_read_b128 frags + 16 barrier pairs instead of 32.
// z: 0 -> Q = x*Wq^T (bf16, pre-scaled); 1 -> K = ctx*Wk^T; 2 -> V^T [b][h][d][m].
__global__ __launch_bounds__(256)
void gemm_qkv(const unsigned short* __restrict__ xb,
              const unsigned short* __restrict__ cb,
              const unsigned short* __restrict__ wqb,
              const unsigned short* __restrict__ wkb,
              const unsigned short* __restrict__ wvb,
              unsigned short* __restrict__ Qb,
              unsigned short* __restrict__ Kb,
              unsigned short* __restrict__ Vtb,
              float qscale)
{
  __shared__ __align__(16) unsigned short As[128 * 64];  // 16KB
  __shared__ __align__(16) unsigned short Bs[128 * 64];  // 16KB
  const int t   = threadIdx.x;
  const int wv  = t >> 6;
  const int ln  = t & 63;
  const int l15 = ln & 15;
  const int qd  = ln >> 4;

  const int L   = blockIdx.x;
  const int xcd = L & 7;
  const int n0  = ((L >> 3) & 7) * 128;
  const int mq  = (L >> 6) & 7;
  const int z   = L >> 9;                 // 0..2
  const int m0  = (mq * 8 + xcd) * 128;

  const int wm  = (wv >> 1) * 64;
  const int wn  = (wv & 1) * 64;

  const unsigned short* A = (z == 0) ? xb : cb;
  const unsigned short* W = (z == 0) ? wqb : (z == 1) ? wkb : wvb;

  const f32x4 vzero = {0.f, 0.f, 0.f, 0.f};
  f32x4 acc[4][4];
#pragma unroll
  for (int i = 0; i < 4; ++i)
#pragma unroll
    for (int j = 0; j < 4; ++j) acc[i][j] = vzero;

  for (int k0 = 0; k0 < KD; k0 += 64) {
    __syncthreads();
#pragma unroll
    for (int l = 0; l < 4; ++l) {
      const int i = l * 256 + wv * 64 + ln;   // 0..1023
      const int row = i >> 3, ch = i & 7;     // 128 rows x 8 chunks(16B)
      const int gch = ch ^ (row & 7);         // XOR-8 source-chunk swizzle
      async16(A + (size_t)(m0 + row) * KD + k0 + gch * 8, As + i * 8);
      async16(W + (size_t)(n0 + row) * KD + k0 + gch * 8, Bs + i * 8);
    }
    __syncthreads();
#pragma unroll
    for (int ks = 0; ks < 2; ++ks) {
      bf16x8 af[4], bfr[4];
#pragma unroll
      for (int mt = 0; mt < 4; ++mt) {
        const int row = wm + mt * 16 + l15;
        af[mt] = ldsv(As + row * 64 + (((ks * 4 + qd) ^ (row & 7)) * 8));
      }
#pragma unroll
      for (int nt = 0; nt < 4; ++nt) {
        const int row = wn + nt * 16 + l15;
        bfr[nt] = ldsv(Bs + row * 64 + (((ks * 4 + qd) ^ (row & 7)) * 8));
      }
#pragma unroll
      for (int mt = 0; mt < 4; ++mt)
#pragma unroll
        for (int nt = 0; nt < 4; ++nt)
          acc[mt][nt] = __builtin_amdgcn_mfma_f32_16x16x32_bf16(af[mt], bfr[nt], acc[mt][nt], 0, 0, 0);
    }
  }

  // epilogue: C/D layout col=l15, row=qd*4+r
  const float scale = (z == 0) ? qscale : 1.0f;
#pragma unroll
  for (int mt = 0; mt < 4; ++mt) {
#pragma unroll
    for (int nt = 0; nt < 4; ++nt) {
      const int col   = n0 + wn + nt * 16 + l15;
      const int rbase = m0 + wm + mt * 16 + qd * 4;
      if (z < 2) {
        unsigned short* outb = (z == 0) ? Qb : Kb;
#pragma unroll
        for (int r = 0; r < 4; ++r)
          outb[(size_t)(rbase + r) * EDIM + col] = f2bf(acc[mt][nt][r] * scale);
      } else {
        const int b = rbase >> 11, m = rbase & 2047;
        const int h = col >> 6,   d = col & 63;
        ushort4 o;
        o.x = f2bf(acc[mt][nt][0]); o.y = f2bf(acc[mt][nt][1]);
        o.z = f2bf(acc[mt][nt][2]); o.w = f2bf(acc[mt][nt][3]);
        *(ushort4*)(Vtb + ((size_t)(b * HEADS + h) * DIMH + d) * SEQM + m) = o;
      }
    }
  }
}

// ---------------- output projection GEMM (fp32 out + bias), XCD-swizzled, BK=64 ----------------
__global__ __launch_bounds__(256)
void gemm_out(const unsigned short* __restrict__ A,
              const unsigned short* __restrict__ W,
              float* __restrict__ outf,
              const float* __restrict__ bias)
{
  __shared__ __align__(16) unsigned short As[128 * 64];
  __shared__ __align__(16) unsigned short Bs[128 * 64];
  const int t   = threadIdx.x;
  const int wv  = t >> 6;
  const int ln  = t & 63;
  const int l15 = ln & 15;
  const int qd  = ln >> 4;

  const int L   = blockIdx.x;
  const int xcd = L & 7;
  const int n0  = ((L >> 3) & 7) * 128;
  const int mq  = L >> 6;                 // 0..7
  const int m0  = (mq * 8 + xcd) * 128;

  const int wm  = (wv >> 1) * 64;
  const int wn  = (wv & 1) * 64;

  const f32x4 vzero = {0.f, 0.f, 0.f, 0.f};
  f32x4 acc[4][4];
#pragma unroll
  for (int i = 0; i < 4; ++i)
#pragma unroll
    for (int j = 0; j < 4; ++j) acc[i][j] = vzero;

  for (int k0 = 0; k0 < KD; k0 += 64) {
    __syncthreads();
#pragma unroll
    for (int l = 0; l < 4; ++l) {
      const int i = l * 256 + wv * 64 + ln;
      const int row = i >> 3, ch = i & 7;
      const int gch = ch ^ (row & 7);
      async16(A + (size_t)(m0 + row) * KD + k0 + gch * 8, As + i * 8);
      async16(W + (size_t)(n0 + row) * KD + k0 + gch * 8, Bs + i * 8);
    }
    __syncthreads();
#pragma unroll
    for (int ks = 0; ks < 2; ++ks) {
      bf16x8 af[4], bfr[4];
#pragma unroll
      for (int mt = 0; mt < 4; ++mt) {
        const int row = wm + mt * 16 + l15;
        af[mt] = ldsv(As + row * 64 + (((ks * 4 + qd) ^ (row & 7)) * 8));
      }
#pragma unroll
      for (int nt = 0; nt < 4; ++nt) {
        const int row = wn + nt * 16 + l15;
        bfr[nt] = ldsv(Bs + row * 64 + (((ks * 4 + qd) ^ (row & 7)) * 8));
      }
#pragma unroll
      for (int mt = 0; mt < 4; ++mt)
#pragma unroll
        for (int nt = 0; nt < 4; ++nt)
          acc[mt][nt] = __builtin_amdgcn_mfma_f32_16x16x32_bf16(af[mt], bfr[nt], acc[mt][nt], 0, 0, 0);
    }
  }

#pragma unroll
  for (int mt = 0; mt < 4; ++mt) {
#pragma unroll
    for (int nt = 0; nt < 4; ++nt) {
      const int col   = n0 + wn + nt * 16 + l15;
      const int rbase = m0 + wm + mt * 16 + qd * 4;
      const float bv = bias[col];
#pragma unroll
      for (int r = 0; r < 4; ++r)
        outf[(size_t)(rbase + r) * EDIM + col] = acc[mt][nt][r] + bv;
    }
  }
}

// ---------------- flash attention (r4 version, frozen) ----------------
__global__ __launch_bounds__(256)
void attn_kernel(const unsigned short* __restrict__ Q,
                 const unsigned short* __restrict__ K,
                 const unsigned short* __restrict__ VT,
                 unsigned short* __restrict__ O)
{
  __shared__ __align__(16) unsigned short Qs[128 * 64];  // aliased as Ps after qf load
  __shared__ __align__(16) unsigned short Ks[64 * 64];
  __shared__ __align__(16) unsigned short Vs[64 * 64];
  unsigned short* Ps = Qs;  // per-wave [qrow 32][j 64], wave wv owns rows [wv*32, wv*32+32)

  const int t   = threadIdx.x;
  const int wv  = t >> 6;
  const int ln  = t & 63;
  const int l15 = ln & 15;
  const int qd  = ln >> 4;

  // XCD-locality decode: L = bh_hi*128 + qt*8 + bh_lo
  const int L      = blockIdx.x;
  const int bh     = ((L >> 7) << 3) | (L & 7);
  const int qt     = (L >> 3) & 15;
  const int q0     = qt * 128;
  const int b      = bh >> 4;      // bh = b*HEADS + h
  const int h      = bh & 15;

  const unsigned short* Qp = Q + (size_t)b * SEQN * EDIM + h * DIMH;
  const unsigned short* Kp = K + (size_t)b * SEQM * EDIM + h * DIMH;
  const unsigned short* Vp = VT + ((size_t)bh) * DIMH * SEQM;

  // stage Q tile (128x64), XOR-swizzled 16B chunks
#pragma unroll
  for (int l = 0; l < 4; ++l) {
    const int i = l * 256 + wv * 64 + ln;     // 0..1023
    const int row = i >> 3, ch = i & 7;
    const int gch = ch ^ (row & 7);
    async16(Qp + (size_t)(q0 + row) * EDIM + gch * 8, Qs + i * 8);
  }
  __syncthreads();

  // Q fragments (used as MFMA B-operand -> acts as Q^T); frees Qs for reuse as Ps
  bf16x8 qf[2][2];
#pragma unroll
  for (int qc = 0; qc < 2; ++qc) {
    const int row = wv * 32 + qc * 16 + l15;
#pragma unroll
    for (int ks = 0; ks < 2; ++ks) {
      const int c = (ks * 4 + qd) ^ (row & 7);
      qf[qc][ks] = ldsv(Qs + row * 64 + c * 8);
    }
  }

  const f32x4 vzero = {0.f, 0.f, 0.f, 0.f};
  f32x4 o_acc[2][4];
#pragma unroll
  for (int qc = 0; qc < 2; ++qc)
#pragma unroll
    for (int dt = 0; dt < 4; ++dt) o_acc[qc][dt] = vzero;

  float rsum[2] = {0.f, 0.f};

  unsigned short* Pw = Ps + wv * 2048;  // wave-private P region (aliases own Q rows)

  for (int j0 = 0; j0 < SEQM; j0 += 64) {
    __syncthreads();
#pragma unroll
    for (int l = 0; l < 2; ++l) {
      const int i = l * 256 + wv * 64 + ln;   // 0..511
      const int row = i >> 3, ch = i & 7;
      const int gch = ch ^ (row & 7);
      async16(Kp + (size_t)(j0 + row) * EDIM + gch * 8, Ks + i * 8);
      async16(Vp + (size_t)row * SEQM + j0 + gch * 8, Vs + i * 8);
    }
    __syncthreads();

    // S^T = K * Q^T   (C-layout: row = j = qd*4+r, col = qrow = l15)
    f32x4 st[2][4];
#pragma unroll
    for (int qc = 0; qc < 2; ++qc)
#pragma unroll
      for (int jt = 0; jt < 4; ++jt) st[qc][jt] = vzero;

#pragma unroll
    for (int jt = 0; jt < 4; ++jt) {
      const int rowj = jt * 16 + l15;
#pragma unroll
      for (int ks = 0; ks < 2; ++ks) {
        const int c = (ks * 4 + qd) ^ (rowj & 7);
        const bf16x8 kf = ldsv(Ks + rowj * 64 + c * 8);
        st[0][jt] = __builtin_amdgcn_mfma_f32_16x16x32_bf16(kf, qf[0][ks], st[0][jt], 0, 0, 0);
        st[1][jt] = __builtin_amdgcn_mfma_f32_16x16x32_bf16(kf, qf[1][ks], st[1][jt], 0, 0, 0);
      }
    }

    // exp + pack + P write (all in-lane; j-consecutive regs; no bias needed)
#pragma unroll
    for (int qc = 0; qc < 2; ++qc) {
      unsigned short* prow = Pw + (qc * 16 + l15) * 64;
#pragma unroll
      for (int jt = 0; jt < 4; ++jt) {
        float p0 = fexp2(st[qc][jt][0]);
        float p1 = fexp2(st[qc][jt][1]);
        float p2 = fexp2(st[qc][jt][2]);
        float p3 = fexp2(st[qc][jt][3]);
        rsum[qc] += (p0 + p1) + (p2 + p3);
        uint2 dw;
        dw.x = pk_bf16(p0, p1);
        dw.y = pk_bf16(p2, p3);
        const int c = (jt * 4 + qd) ^ l15;       // b64-chunk swizzle (bank-uniform)
        *(uint2*)(prow + c * 4) = dw;
      }
    }
    asm volatile("" ::: "memory");  // keep Ps writes before reads (same-wave DS in-order)

    // O += P * V
#pragma unroll
    for (int ks2 = 0; ks2 < 2; ++ks2) {
      bf16x8 pf[2];
#pragma unroll
      for (int qc = 0; qc < 2; ++qc) {
        const unsigned short* prow = Pw + (qc * 16 + l15) * 64;
        const int c0 = ks2 * 8 + qd * 2;
        uint2 lo = *(const uint2*)(prow + ((c0)     ^ l15) * 4);
        uint2 hi = *(const uint2*)(prow + ((c0 + 1) ^ l15) * 4);
        union { uint32_t u[4]; bf16x8 v; } cc;
        cc.u[0] = lo.x; cc.u[1] = lo.y; cc.u[2] = hi.x; cc.u[3] = hi.y;
        pf[qc] = cc.v;
      }
#pragma unroll
      for (int dt = 0; dt < 4; ++dt) {
        const int rowd = dt * 16 + l15;
        const int c = (ks2 * 4 + qd) ^ (rowd & 7);
        const bf16x8 vf = ldsv(Vs + rowd * 64 + c * 8);
        o_acc[0][dt] = __builtin_amdgcn_mfma_f32_16x16x32_bf16(pf[0], vf, o_acc[0][dt], 0, 0, 0);
        o_acc[1][dt] = __builtin_amdgcn_mfma_f32_16x16x32_bf16(pf[1], vf, o_acc[1][dt], 0, 0, 0);
      }
    }
  }

  // final l reduction: per-lane partial -> full sum per qrow (over qd groups)
#pragma unroll
  for (int qc = 0; qc < 2; ++qc) {
    float r = rsum[qc];
    r += __shfl_xor(r, 16);
    r += __shfl_xor(r, 32);
    rsum[qc] = r;  // every lane now has l for qrow = qc*16 + l15
  }

  // normalize + write O (bf16 row-major)
  unsigned short* Op = O + (size_t)b * SEQN * EDIM + h * DIMH;
#pragma unroll
  for (int qc = 0; qc < 2; ++qc) {
    float inv[4];
#pragma unroll
    for (int r = 0; r < 4; ++r)
      inv[r] = 1.0f / __shfl(rsum[qc], qd * 4 + r);  // l for qrow = qc*16 + qd*4 + r
#pragma unroll
    for (int dt = 0; dt < 4; ++dt) {
      const int col = dt * 16 + l15;
#pragma unroll
      for (int r = 0; r < 4; ++r) {
        const int row = q0 + wv * 32 + qc * 16 + qd * 4 + r;
        Op[(size_t)row * EDIM + col] = f2bf(o_acc[qc][dt][r] * inv[r]);
      }
    }
  }
}

// ---------------- launch ----------------
extern "C" void kernel_launch(void* const* d_in, const int* in_sizes, int n_in,
                              void* d_out, int out_size, void* d_ws, size_t ws_size,
                              hipStream_t stream) {
  const float* x   = (const float*)d_in[0];
  const float* ctx = (const float*)d_in[1];
  const float* Wq  = (const float*)d_in[2];
  const float* Wk  = (const float*)d_in[3];
  const float* Wv  = (const float*)d_in[4];
  const float* Wo  = (const float*)d_in[5];
  const float* bo  = (const float*)d_in[6];
  float* out = (float*)d_out;

  char* ws = (char*)d_ws;
  const size_t SZ_X = (size_t)NB * SEQN * EDIM * 2;  // 16 MiB (bf16 activations)
  const size_t SZ_W = (size_t)EDIM * KD * 2;         // 2 MiB  (bf16 weights)
  unsigned short* xb  = (unsigned short*)(ws);
  unsigned short* cb  = (unsigned short*)(ws + SZ_X);
  unsigned short* wqb = (unsigned short*)(ws + 2 * SZ_X);
  unsigned short* wkb = (unsigned short*)(ws + 2 * SZ_X + SZ_W);
  unsigned short* wvb = (unsigned short*)(ws + 2 * SZ_X + 2 * SZ_W);
  unsigned short* wob = (unsigned short*)(ws + 2 * SZ_X + 3 * SZ_W);
  unsigned short* Qb  = (unsigned short*)(ws + 2 * SZ_X + 4 * SZ_W);
  unsigned short* Kb  = (unsigned short*)(ws + 3 * SZ_X + 4 * SZ_W);
  unsigned short* Vtb = (unsigned short*)(ws + 4 * SZ_X + 4 * SZ_W);
  unsigned short* Ob  = (unsigned short*)(ws + 5 * SZ_X + 4 * SZ_W);

  const float SCL2E = 0.125f * 1.4426950408889634f;  // dim_head^-0.5 * log2(e)
  const dim3 blk(256);

  // 6 segments: x (8192 blocks), ctx (8192), Wq/Wk/Wv/Wo (1024 each)
  cvt_all<<<dim3(20480), blk, 0, stream>>>(
      (const float4*)x, (const float4*)ctx, (const float4*)Wq, (const float4*)Wk,
      (const float4*)Wv, (const float4*)Wo,
      (ushort4*)xb, (ushort4*)cb, (ushort4*)wqb, (ushort4*)wkb,
      (ushort4*)wvb, (ushort4*)wob);

  gemm_qkv<<<dim3(1536), blk, 0, stream>>>(
      xb, cb, wqb, wkb, wvb, Qb, Kb, Vtb, SCL2E);

  attn_kernel<<<dim3(1024), blk, 0, stream>>>(Qb, Kb, Vtb, Ob);

  gemm_out<<<dim3(512), blk, 0, stream>>>(Ob, wob, out, bo);
}